// Round 9
// baseline (661.155 us; speedup 1.0000x reference)
//
#include <hip/hip_runtime.h>
#include <math.h>

#define NPTS 4096
#define BLK 256
#define V 64
#define NPROJ 256
#define NBATCH 32

// R9: R8's validated single-wave sort (V=64, trips T1..T9 + cleaners C1..C9),
// but the x-wave and y-wave of a (b,p) pair TIME-SHARE one 16 KB LDS buffer:
// barriers alternate buffer ownership; the non-owner runs its register-only
// cleaner stages. Each trip fully drains LDS back to registers, so the buffer
// is free at every barrier. BLK=256 = 2 pairs x 2 waves, 2 buffers = 32 KB
// -> 4 sort-waves per 32 KB (2x R8's waves-per-LDS-byte) -> up to 20
// sort-waves/CU resident, finally giving the SIMDs enough independent waves
// to overlap VALU with LDS latency.
// Layouts (element idx, 12 bits; T=wave-lane 6b, c=chunk 4b, l=comp 2b):
//   A: T=idx[11:6], c=idx[5:2]                (regs = idx[5:0])
//   B: T={idx[11:10],idx[5:2]}, c=idx[9:6]    (regs = {idx[9:6],idx[1:0]})
//   C: T=idx[9:4],  c={idx[11:10],idx[3:2]}   (regs = {idx[11:10],idx[3:0]})
// float4-slot placement: A/B: slot=(T<<4)|(c^(T&15)); C: slot=(T<<4)|(c^(T>>2&15)).
// All patterns bank-even (8 dwords/bank per b128) and bijective (verified,
// absmax 0 in R8). Normalized bitonic: merges 2..64 in-reg; m128/m256 via
// shfl_xor; m512..m4096 via LDS trips with reversal fused into reads.

__device__ __forceinline__ void cmpex_asc(float& a, float& b) {
    const float lo = fminf(a, b), hi = fmaxf(a, b);
    a = lo; b = hi;
}

template<int JB, int JL>
__device__ __forceinline__ void stages(float* v) {
#pragma unroll
    for (int r = 0; r < V; ++r)
        if ((r & JB) == 0) cmpex_asc(v[r], v[r | JB]);
    if constexpr (JB > JL) stages<(JB >> 1), JL>(v);
}

template<int MASK>
__device__ __forceinline__ void rev_inreg(float* v) {
    constexpr int S = (MASK + 1) >> 1;
#pragma unroll
    for (int r = 0; r < V; ++r) {
        if ((r & S) == 0) {
            const float a = v[r], b = v[r ^ MASK];
            v[r] = fminf(a, b);
            v[r ^ MASK] = fmaxf(a, b);
        }
    }
}

// Reversal across thread-pair (xor XM), registers reversed (r <-> 63-r).
template<int XM>
__device__ __forceinline__ void rev_shfl(float* v, bool hi) {
#pragma unroll
    for (int r = 0; r < 32; ++r) {
        const float pa = __shfl_xor(v[63 - r], XM, 64);
        const float pb = __shfl_xor(v[r], XM, 64);
        v[r]      = hi ? fmaxf(v[r], pa)      : fminf(v[r], pa);
        v[63 - r] = hi ? fmaxf(v[63 - r], pb) : fminf(v[63 - r], pb);
    }
}
// Same-register cross-thread stage (xor XM).
template<int XM>
__device__ __forceinline__ void stage_shfl(float* v, bool hi) {
#pragma unroll
    for (int r = 0; r < V; ++r) {
        const float q = __shfl_xor(v[r], XM, 64);
        v[r] = hi ? fmaxf(v[r], q) : fminf(v[r], q);
    }
}

// A->B and B->A scatter-write (same formula, symmetric).
__device__ __forceinline__ void write_AB(float* s, const float* v, int sAB, int t15) {
    float4* s4 = (float4*)s;
#pragma unroll
    for (int c = 0; c < 16; ++c)
        s4[sAB | (c << 4) | (t15 ^ c)] =
            make_float4(v[4*c], v[4*c+1], v[4*c+2], v[4*c+3]);
}
// Natural (own-slot) write, A/B-resident layout.
__device__ __forceinline__ void write_own(float* s, const float* v, int t, int t15) {
    float4* s4 = (float4*)s;
#pragma unroll
    for (int c = 0; c < 16; ++c)
        s4[(t << 4) | (c ^ t15)] =
            make_float4(v[4*c], v[4*c+1], v[4*c+2], v[4*c+3]);
}
// Own-slot read, valid for A- and B-resident phases.
__device__ __forceinline__ void read_own(const float* s, float* v, int t, int t15) {
    const float4* s4 = (const float4*)s;
#pragma unroll
    for (int c = 0; c < 16; ++c) {
        const float4 f = s4[(t << 4) | (c ^ t15)];
        v[4*c] = f.x; v[4*c+1] = f.y; v[4*c+2] = f.z; v[4*c+3] = f.w;
    }
}
// B-entry read fused with reversal: own + partner (t^PM, c^CM, comps
// reversed). Keep side: chunk bit KB, or thread-uniform thi when KB==0.
template<int PM, int CM, int KB>
__device__ __forceinline__ void read_rev_B(const float* s, float* v, int t, int t15, bool thi) {
    const float4* s4 = (const float4*)s;
    const int pt = t ^ PM, pt15 = t15 ^ (PM & 15);
#pragma unroll
    for (int c = 0; c < 16; ++c) {
        const float4 o = s4[(t << 4) | (c ^ t15)];
        const float4 q = s4[(pt << 4) | ((c ^ CM) ^ pt15)];
        const bool mx = KB ? ((c & KB) != 0) : thi;
        v[4*c+0] = mx ? fmaxf(o.x, q.w) : fminf(o.x, q.w);
        v[4*c+1] = mx ? fmaxf(o.y, q.z) : fminf(o.y, q.z);
        v[4*c+2] = mx ? fmaxf(o.z, q.y) : fminf(o.z, q.y);
        v[4*c+3] = mx ? fmaxf(o.w, q.x) : fminf(o.w, q.x);
    }
}
// A->C scatter-write.
__device__ __forceinline__ void write_AC(float* s, const float* v, int t15, int qAC) {
    float4* s4 = (float4*)s;
#pragma unroll
    for (int c = 0; c < 16; ++c)
        s4[(t15 << 6) | ((c >> 2) << 4) | (qAC ^ (c & 3))] =
            make_float4(v[4*c], v[4*c+1], v[4*c+2], v[4*c+3]);
}
// C-entry read fused with m4096 reversal (partner t^63, c^15, keep c&8).
__device__ __forceinline__ void read_rev_C(const float* s, float* v, int t, int th) {
    const float4* s4 = (const float4*)s;
    const int pt = t ^ 63, pth = th ^ 15;
#pragma unroll
    for (int c = 0; c < 16; ++c) {
        const float4 o = s4[(t << 4) | (c ^ th)];
        const float4 q = s4[(pt << 4) | ((c ^ 15) ^ pth)];
        const bool mx = (c & 8) != 0;
        v[4*c+0] = mx ? fmaxf(o.x, q.w) : fminf(o.x, q.w);
        v[4*c+1] = mx ? fmaxf(o.y, q.z) : fminf(o.y, q.z);
        v[4*c+2] = mx ? fmaxf(o.z, q.y) : fminf(o.z, q.y);
        v[4*c+3] = mx ? fmaxf(o.w, q.x) : fminf(o.w, q.x);
    }
}
// C->B scatter-write.
__device__ __forceinline__ void write_CB(float* s, const float* v, int sCB, int qCB) {
    float4* s4 = (float4*)s;
#pragma unroll
    for (int c = 0; c < 16; ++c)
        s4[((c >> 2) << 8) | sCB | ((c & 3) << 4) | (qCB ^ (c & 3))] =
            make_float4(v[4*c], v[4*c+1], v[4*c+2], v[4*c+3]);
}

__device__ __forceinline__ void load_project(const float* base, float* v,
                                             float p0, float p1, float p2) {
    const float4* b4 = (const float4*)base;
#pragma unroll
    for (int g = 0; g < 16; ++g) {
        float4 a = b4[g * 3 + 0], c = b4[g * 3 + 1], d = b4[g * 3 + 2];
        v[4*g+0] = a.x * p0 + a.y * p1 + a.z * p2;
        v[4*g+1] = a.w * p0 + c.x * p1 + c.y * p2;
        v[4*g+2] = c.z * p0 + c.w * p1 + d.x * p2;
        v[4*g+3] = d.y * p0 + d.z * p1 + d.w * p2;
    }
}

__global__ __launch_bounds__(BLK, 4) void swd_kernel(
    const float* __restrict__ x, const float* __restrict__ y,
    const float* __restrict__ theta, const float* __restrict__ rot,
    float* __restrict__ per_batch) {
    __shared__ float buf2[2][NPTS];   // one 16 KB buffer per (b,p) pair

    const int t = threadIdx.x & 63;           // wave lane
    const int w = (threadIdx.x >> 6) & 1;     // 0: x-wave, 1: y-wave of the pair
    const int pairId = threadIdx.x >> 7;      // 2 pairs per block
    const int p = blockIdx.x * 2 + pairId;
    const int b = blockIdx.y;

    const float t0 = theta[p * 3 + 0], t1 = theta[p * 3 + 1], t2 = theta[p * 3 + 2];
    const float* R = rot + b * 9;
    const float p0 = t0 * R[0] + t1 * R[3] + t2 * R[6];
    const float p1 = t0 * R[1] + t1 * R[4] + t2 * R[7];
    const float p2 = t0 * R[2] + t1 * R[5] + t2 * R[8];

    float* buf = buf2[pairId];
    const float* src = w ? y : x;

    float v[V];
    load_project(src + (size_t)b * NPTS * 3 + (size_t)t * V * 3, v, p0, p1, p2);

    // Addressing precompute (as R8).
    const int t15 = t & 15;
    const int sAB = (t >> 4) << 8;
    const int qAC = ((t >> 4) << 2) ^ t15;
    const int th  = (t >> 2) & 15;
    const int sCB = (t & 3) << 6;
    const int qCB = (t >> 2) ^ ((t & 3) << 2);
    const bool hi1  = (t & 1) != 0;
    const bool hi2  = (t & 2) != 0;
    const bool hi16 = (t & 16) != 0;

    // ---- in-reg prelude: merges 2..256 (no LDS) ----
    rev_inreg<1>(v);
    rev_inreg<3>(v);  stages<1, 1>(v);
    rev_inreg<7>(v);  stages<2, 1>(v);
    rev_inreg<15>(v); stages<4, 1>(v);
    rev_inreg<31>(v); stages<8, 1>(v);
    rev_inreg<63>(v); stages<16, 1>(v);
    rev_shfl<1>(v, hi1);
    stages<32, 1>(v);
    rev_shfl<3>(v, hi2);
    stage_shfl<2>(v, hi2);
    stage_shfl<1>(v, hi1);
    stages<32, 1>(v);

    // ---- slot-scheduled LDS trips: per wave, sequence T1 C1 T2 C2 ... T9 C9
    // (identical to validated R8), buffer ownership alternates per barrier.
#define T_REV512  { write_AB(buf, v, sAB, t15); read_rev_B<15, 7, 4>(buf, v, t, t15, false); }
#define T_REV1024 { write_AB(buf, v, sAB, t15); read_rev_B<15, 15, 8>(buf, v, t, t15, false); }
#define T_REV2048 { write_AB(buf, v, sAB, t15); read_rev_B<31, 15, 0>(buf, v, t, t15, hi16); }
#define T_OWN     { write_AB(buf, v, sAB, t15); read_own(buf, v, t, t15); }
#define T_AC4096  { write_AC(buf, v, t15, qAC); read_rev_C(buf, v, t, th); }
#define T_CB4096  { write_CB(buf, v, sCB, qCB); read_own(buf, v, t, t15); }
#define SYNC __syncthreads();

    SYNC if (!w) T_REV512                                   // s1
    SYNC if (w)  T_REV512  else { stages<8, 4>(v); }        // s2
    SYNC if (!w) T_OWN     else { stages<8, 4>(v); }        // s3
    SYNC if (w)  T_OWN     else { stages<32, 1>(v); }       // s4
    SYNC if (!w) T_REV1024 else { stages<32, 1>(v); }       // s5
    SYNC if (w)  T_REV1024 else { stages<16, 4>(v); }       // s6
    SYNC if (!w) T_OWN     else { stages<16, 4>(v); }       // s7
    SYNC if (w)  T_OWN     else { stages<32, 1>(v); }       // s8
    SYNC if (!w) T_REV2048 else { stages<32, 1>(v); }       // s9
    SYNC if (w)  T_REV2048 else { stages<32, 4>(v); }       // s10
    SYNC if (!w) T_OWN     else { stages<32, 4>(v); }       // s11
    SYNC if (w)  T_OWN     else { stages<32, 1>(v); }       // s12
    SYNC if (!w) T_AC4096  else { stages<32, 1>(v); }       // s13
    SYNC if (w)  T_AC4096  else { stages<16, 16>(v); }      // s14
    SYNC if (!w) T_CB4096  else { stages<16, 16>(v); }      // s15
    SYNC if (w)  T_CB4096  else { stages<32, 4>(v); }       // s16
    SYNC if (!w) T_OWN     else { stages<32, 4>(v); }       // s17
    SYNC if (w)  T_OWN     else { stages<32, 1>(v); }       // s18
    SYNC if (w)  { stages<32, 1>(v); write_own(buf, v, t, t15); }  // s19: y publish
    SYNC                                                     // s20
    if (!w) {
        float yv[V];
        read_own(buf, yv, t, t15);
        float s = 0.0f;
#pragma unroll
        for (int r = 0; r < V; ++r) {
            const float d = v[r] - yv[r];
            s += d * d;
        }
        for (int off = 32; off > 0; off >>= 1) s += __shfl_down(s, off, 64);
        if (t == 0) atomicAdd(&per_batch[b], s);
    }
}

__global__ void finalize_kernel(const float* __restrict__ per_batch, float* __restrict__ out) {
    const int t = threadIdx.x;  // 64 threads
    float v = (t < NBATCH) ? sqrtf(per_batch[t] * (1.0f / (float)NPROJ)) : 0.0f;
    for (int off = 32; off > 0; off >>= 1) v += __shfl_down(v, off, 64);
    if (t == 0) out[0] = v * (1.0f / (float)NBATCH);
}

extern "C" void kernel_launch(void* const* d_in, const int* in_sizes, int n_in,
                              void* d_out, int out_size, void* d_ws, size_t ws_size,
                              hipStream_t stream) {
    const float* x = (const float*)d_in[0];
    const float* y = (const float*)d_in[1];
    const float* theta = (const float*)d_in[2];
    const float* rot = (const float*)d_in[3];
    float* per_batch = (float*)d_ws;
    float* out = (float*)d_out;

    hipMemsetAsync(per_batch, 0, NBATCH * sizeof(float), stream);

    dim3 grid(NPROJ / 2, NBATCH);
    swd_kernel<<<grid, BLK, 0, stream>>>(x, y, theta, rot, per_batch);

    finalize_kernel<<<1, 64, 0, stream>>>(per_batch, out);
}

// Round 10
// 405.678 us; speedup vs baseline: 1.6298x; 1.6298x over previous
//
#include <hip/hip_runtime.h>
#include <math.h>

#define NPTS 4096
#define BLK 256
#define V 64
#define NPROJ 256
#define NBATCH 32

// R10 = R9 schedule with corrected __launch_bounds__(256, 2).
// R9's (256,4) demanded 4 waves/EU -> VGPR cap 64 -> v[64] spilled to
// scratch (950 MB writes). (256,2) -> cap 256; actual need ~84 (R8-proven).
// Structure: x-wave and y-wave of a (b,p) pair TIME-SHARE one 16 KB LDS
// buffer; barriers alternate ownership; non-owner runs register-only cleaner
// stages. 2 pairs per 256-thread block, 32 KB LDS -> 5 blocks/CU -> ~20
// resident sort-waves/CU (2.5x R8), overlapping VALU with LDS trips.
// Layouts (element idx, 12 bits; T=wave-lane 6b, c=chunk 4b, l=comp 2b):
//   A: T=idx[11:6], c=idx[5:2]                (regs = idx[5:0])
//   B: T={idx[11:10],idx[5:2]}, c=idx[9:6]    (regs = {idx[9:6],idx[1:0]})
//   C: T=idx[9:4],  c={idx[11:10],idx[3:2]}   (regs = {idx[11:10],idx[3:0]})
// float4-slot placement: A/B: slot=(T<<4)|(c^(T&15)); C: slot=(T<<4)|(c^(T>>2&15)).
// All patterns bank-even and bijective (absmax 0 in R8/R9). Normalized
// bitonic: merges 2..256 in-reg/shfl; m512..m4096 via LDS trips with
// reversal fused into reads.

__device__ __forceinline__ void cmpex_asc(float& a, float& b) {
    const float lo = fminf(a, b), hi = fmaxf(a, b);
    a = lo; b = hi;
}

template<int JB, int JL>
__device__ __forceinline__ void stages(float* v) {
#pragma unroll
    for (int r = 0; r < V; ++r)
        if ((r & JB) == 0) cmpex_asc(v[r], v[r | JB]);
    if constexpr (JB > JL) stages<(JB >> 1), JL>(v);
}

template<int MASK>
__device__ __forceinline__ void rev_inreg(float* v) {
    constexpr int S = (MASK + 1) >> 1;
#pragma unroll
    for (int r = 0; r < V; ++r) {
        if ((r & S) == 0) {
            const float a = v[r], b = v[r ^ MASK];
            v[r] = fminf(a, b);
            v[r ^ MASK] = fmaxf(a, b);
        }
    }
}

// Reversal across thread-pair (xor XM), registers reversed (r <-> 63-r).
template<int XM>
__device__ __forceinline__ void rev_shfl(float* v, bool hi) {
#pragma unroll
    for (int r = 0; r < 32; ++r) {
        const float pa = __shfl_xor(v[63 - r], XM, 64);
        const float pb = __shfl_xor(v[r], XM, 64);
        v[r]      = hi ? fmaxf(v[r], pa)      : fminf(v[r], pa);
        v[63 - r] = hi ? fmaxf(v[63 - r], pb) : fminf(v[63 - r], pb);
    }
}
// Same-register cross-thread stage (xor XM).
template<int XM>
__device__ __forceinline__ void stage_shfl(float* v, bool hi) {
#pragma unroll
    for (int r = 0; r < V; ++r) {
        const float q = __shfl_xor(v[r], XM, 64);
        v[r] = hi ? fmaxf(v[r], q) : fminf(v[r], q);
    }
}

// A->B and B->A scatter-write (same formula, symmetric).
__device__ __forceinline__ void write_AB(float* s, const float* v, int sAB, int t15) {
    float4* s4 = (float4*)s;
#pragma unroll
    for (int c = 0; c < 16; ++c)
        s4[sAB | (c << 4) | (t15 ^ c)] =
            make_float4(v[4*c], v[4*c+1], v[4*c+2], v[4*c+3]);
}
// Natural (own-slot) write, A/B-resident layout.
__device__ __forceinline__ void write_own(float* s, const float* v, int t, int t15) {
    float4* s4 = (float4*)s;
#pragma unroll
    for (int c = 0; c < 16; ++c)
        s4[(t << 4) | (c ^ t15)] =
            make_float4(v[4*c], v[4*c+1], v[4*c+2], v[4*c+3]);
}
// Own-slot read, valid for A- and B-resident phases.
__device__ __forceinline__ void read_own(const float* s, float* v, int t, int t15) {
    const float4* s4 = (const float4*)s;
#pragma unroll
    for (int c = 0; c < 16; ++c) {
        const float4 f = s4[(t << 4) | (c ^ t15)];
        v[4*c] = f.x; v[4*c+1] = f.y; v[4*c+2] = f.z; v[4*c+3] = f.w;
    }
}
// B-entry read fused with reversal: own + partner (t^PM, c^CM, comps
// reversed). Keep side: chunk bit KB, or thread-uniform thi when KB==0.
template<int PM, int CM, int KB>
__device__ __forceinline__ void read_rev_B(const float* s, float* v, int t, int t15, bool thi) {
    const float4* s4 = (const float4*)s;
    const int pt = t ^ PM, pt15 = t15 ^ (PM & 15);
#pragma unroll
    for (int c = 0; c < 16; ++c) {
        const float4 o = s4[(t << 4) | (c ^ t15)];
        const float4 q = s4[(pt << 4) | ((c ^ CM) ^ pt15)];
        const bool mx = KB ? ((c & KB) != 0) : thi;
        v[4*c+0] = mx ? fmaxf(o.x, q.w) : fminf(o.x, q.w);
        v[4*c+1] = mx ? fmaxf(o.y, q.z) : fminf(o.y, q.z);
        v[4*c+2] = mx ? fmaxf(o.z, q.y) : fminf(o.z, q.y);
        v[4*c+3] = mx ? fmaxf(o.w, q.x) : fminf(o.w, q.x);
    }
}
// A->C scatter-write.
__device__ __forceinline__ void write_AC(float* s, const float* v, int t15, int qAC) {
    float4* s4 = (float4*)s;
#pragma unroll
    for (int c = 0; c < 16; ++c)
        s4[(t15 << 6) | ((c >> 2) << 4) | (qAC ^ (c & 3))] =
            make_float4(v[4*c], v[4*c+1], v[4*c+2], v[4*c+3]);
}
// C-entry read fused with m4096 reversal (partner t^63, c^15, keep c&8).
__device__ __forceinline__ void read_rev_C(const float* s, float* v, int t, int th) {
    const float4* s4 = (const float4*)s;
    const int pt = t ^ 63, pth = th ^ 15;
#pragma unroll
    for (int c = 0; c < 16; ++c) {
        const float4 o = s4[(t << 4) | (c ^ th)];
        const float4 q = s4[(pt << 4) | ((c ^ 15) ^ pth)];
        const bool mx = (c & 8) != 0;
        v[4*c+0] = mx ? fmaxf(o.x, q.w) : fminf(o.x, q.w);
        v[4*c+1] = mx ? fmaxf(o.y, q.z) : fminf(o.y, q.z);
        v[4*c+2] = mx ? fmaxf(o.z, q.y) : fminf(o.z, q.y);
        v[4*c+3] = mx ? fmaxf(o.w, q.x) : fminf(o.w, q.x);
    }
}
// C->B scatter-write.
__device__ __forceinline__ void write_CB(float* s, const float* v, int sCB, int qCB) {
    float4* s4 = (float4*)s;
#pragma unroll
    for (int c = 0; c < 16; ++c)
        s4[((c >> 2) << 8) | sCB | ((c & 3) << 4) | (qCB ^ (c & 3))] =
            make_float4(v[4*c], v[4*c+1], v[4*c+2], v[4*c+3]);
}

__device__ __forceinline__ void load_project(const float* base, float* v,
                                             float p0, float p1, float p2) {
    const float4* b4 = (const float4*)base;
#pragma unroll
    for (int g = 0; g < 16; ++g) {
        float4 a = b4[g * 3 + 0], c = b4[g * 3 + 1], d = b4[g * 3 + 2];
        v[4*g+0] = a.x * p0 + a.y * p1 + a.z * p2;
        v[4*g+1] = a.w * p0 + c.x * p1 + c.y * p2;
        v[4*g+2] = c.z * p0 + c.w * p1 + d.x * p2;
        v[4*g+3] = d.y * p0 + d.z * p1 + d.w * p2;
    }
}

__global__ __launch_bounds__(BLK, 2) void swd_kernel(
    const float* __restrict__ x, const float* __restrict__ y,
    const float* __restrict__ theta, const float* __restrict__ rot,
    float* __restrict__ per_batch) {
    __shared__ float buf2[2][NPTS];   // one 16 KB buffer per (b,p) pair

    const int t = threadIdx.x & 63;           // wave lane
    const int w = (threadIdx.x >> 6) & 1;     // 0: x-wave, 1: y-wave of the pair
    const int pairId = threadIdx.x >> 7;      // 2 pairs per block
    const int p = blockIdx.x * 2 + pairId;
    const int b = blockIdx.y;

    const float t0 = theta[p * 3 + 0], t1 = theta[p * 3 + 1], t2 = theta[p * 3 + 2];
    const float* R = rot + b * 9;
    const float p0 = t0 * R[0] + t1 * R[3] + t2 * R[6];
    const float p1 = t0 * R[1] + t1 * R[4] + t2 * R[7];
    const float p2 = t0 * R[2] + t1 * R[5] + t2 * R[8];

    float* buf = buf2[pairId];
    const float* src = w ? y : x;

    float v[V];
    load_project(src + (size_t)b * NPTS * 3 + (size_t)t * V * 3, v, p0, p1, p2);

    // Addressing precompute (as R8).
    const int t15 = t & 15;
    const int sAB = (t >> 4) << 8;
    const int qAC = ((t >> 4) << 2) ^ t15;
    const int th  = (t >> 2) & 15;
    const int sCB = (t & 3) << 6;
    const int qCB = (t >> 2) ^ ((t & 3) << 2);
    const bool hi1  = (t & 1) != 0;
    const bool hi2  = (t & 2) != 0;
    const bool hi16 = (t & 16) != 0;

    // ---- in-reg prelude: merges 2..256 (no LDS) ----
    rev_inreg<1>(v);
    rev_inreg<3>(v);  stages<1, 1>(v);
    rev_inreg<7>(v);  stages<2, 1>(v);
    rev_inreg<15>(v); stages<4, 1>(v);
    rev_inreg<31>(v); stages<8, 1>(v);
    rev_inreg<63>(v); stages<16, 1>(v);
    rev_shfl<1>(v, hi1);
    stages<32, 1>(v);
    rev_shfl<3>(v, hi2);
    stage_shfl<2>(v, hi2);
    stage_shfl<1>(v, hi1);
    stages<32, 1>(v);

    // ---- slot-scheduled LDS trips: per wave, sequence T1 C1 T2 C2 ... T9 C9
    // (identical to validated R8/R9), buffer ownership alternates per barrier.
#define T_REV512  { write_AB(buf, v, sAB, t15); read_rev_B<15, 7, 4>(buf, v, t, t15, false); }
#define T_REV1024 { write_AB(buf, v, sAB, t15); read_rev_B<15, 15, 8>(buf, v, t, t15, false); }
#define T_REV2048 { write_AB(buf, v, sAB, t15); read_rev_B<31, 15, 0>(buf, v, t, t15, hi16); }
#define T_OWN     { write_AB(buf, v, sAB, t15); read_own(buf, v, t, t15); }
#define T_AC4096  { write_AC(buf, v, t15, qAC); read_rev_C(buf, v, t, th); }
#define T_CB4096  { write_CB(buf, v, sCB, qCB); read_own(buf, v, t, t15); }
#define SYNC __syncthreads();

    SYNC if (!w) T_REV512                                   // s1
    SYNC if (w)  T_REV512  else { stages<8, 4>(v); }        // s2
    SYNC if (!w) T_OWN     else { stages<8, 4>(v); }        // s3
    SYNC if (w)  T_OWN     else { stages<32, 1>(v); }       // s4
    SYNC if (!w) T_REV1024 else { stages<32, 1>(v); }       // s5
    SYNC if (w)  T_REV1024 else { stages<16, 4>(v); }       // s6
    SYNC if (!w) T_OWN     else { stages<16, 4>(v); }       // s7
    SYNC if (w)  T_OWN     else { stages<32, 1>(v); }       // s8
    SYNC if (!w) T_REV2048 else { stages<32, 1>(v); }       // s9
    SYNC if (w)  T_REV2048 else { stages<32, 4>(v); }       // s10
    SYNC if (!w) T_OWN     else { stages<32, 4>(v); }       // s11
    SYNC if (w)  T_OWN     else { stages<32, 1>(v); }       // s12
    SYNC if (!w) T_AC4096  else { stages<32, 1>(v); }       // s13
    SYNC if (w)  T_AC4096  else { stages<16, 16>(v); }      // s14
    SYNC if (!w) T_CB4096  else { stages<16, 16>(v); }      // s15
    SYNC if (w)  T_CB4096  else { stages<32, 4>(v); }       // s16
    SYNC if (!w) T_OWN     else { stages<32, 4>(v); }       // s17
    SYNC if (w)  T_OWN     else { stages<32, 1>(v); }       // s18
    SYNC if (w)  { stages<32, 1>(v); write_own(buf, v, t, t15); }  // s19: y publish
    SYNC                                                     // s20
    if (!w) {
        float yv[V];
        read_own(buf, yv, t, t15);
        float s = 0.0f;
#pragma unroll
        for (int r = 0; r < V; ++r) {
            const float d = v[r] - yv[r];
            s += d * d;
        }
        for (int off = 32; off > 0; off >>= 1) s += __shfl_down(s, off, 64);
        if (t == 0) atomicAdd(&per_batch[b], s);
    }
}

__global__ void finalize_kernel(const float* __restrict__ per_batch, float* __restrict__ out) {
    const int t = threadIdx.x;  // 64 threads
    float v = (t < NBATCH) ? sqrtf(per_batch[t] * (1.0f / (float)NPROJ)) : 0.0f;
    for (int off = 32; off > 0; off >>= 1) v += __shfl_down(v, off, 64);
    if (t == 0) out[0] = v * (1.0f / (float)NBATCH);
}

extern "C" void kernel_launch(void* const* d_in, const int* in_sizes, int n_in,
                              void* d_out, int out_size, void* d_ws, size_t ws_size,
                              hipStream_t stream) {
    const float* x = (const float*)d_in[0];
    const float* y = (const float*)d_in[1];
    const float* theta = (const float*)d_in[2];
    const float* rot = (const float*)d_in[3];
    float* per_batch = (float*)d_ws;
    float* out = (float*)d_out;

    hipMemsetAsync(per_batch, 0, NBATCH * sizeof(float), stream);

    dim3 grid(NPROJ / 2, NBATCH);
    swd_kernel<<<grid, BLK, 0, stream>>>(x, y, theta, rot, per_batch);

    finalize_kernel<<<1, 64, 0, stream>>>(per_batch, out);
}